// Round 1
// baseline (190.368 us; speedup 1.0000x reference)
//
#include <hip/hip_runtime.h>
#include <math.h>

typedef unsigned short u16;
typedef __attribute__((ext_vector_type(8))) short short8v;
typedef __attribute__((ext_vector_type(4))) float f32x4v;
typedef __attribute__((ext_vector_type(4))) unsigned short u16x4;

#define GLOAD_LDS16(src, dst)                                      \
  __builtin_amdgcn_global_load_lds(                                \
      (const __attribute__((address_space(1))) void*)(src),        \
      (__attribute__((address_space(3))) void*)(dst), 16, 0, 0)

__device__ __forceinline__ u16 f2bf(float f) {
  union { float f; unsigned u; } v; v.f = f;
  unsigned r = v.u + 0x7FFFu + ((v.u >> 16) & 1u);  // RNE
  return (u16)(r >> 16);
}

// ---------------------------------------------------------------------------
// K_adj: read adj f32 once; per-block partial row sums (deterministic) and
// bf16 TRANSPOSED copy adjT[i][j] = adj[j][i] via LDS transpose.
// Tile: 64 rows x 256 cols. grid = (32, 128).
// ---------------------------------------------------------------------------
__global__ __launch_bounds__(256) void k_adj(const float* __restrict__ adj,
                                             u16* __restrict__ adjT,
                                             float* __restrict__ rsP) {
  __shared__ __align__(16) char Tsm[32768];  // 256 rows(c) x 128B, chunk-swizzled
  const int tid = threadIdx.x, l = tid & 63, w = tid >> 6;
  const int c0 = blockIdx.x * 256, r0 = blockIdx.y * 64;
  for (int p = 0; p < 16; ++p) {
    const int rr = p * 4 + w;                 // one row per wave per pass
    const float4 v = *(const float4*)(adj + (size_t)(r0 + rr) * 8192 + c0 + l * 4);
    float s = v.x + v.y + v.z + v.w;
#pragma unroll
    for (int off = 32; off > 0; off >>= 1) s += __shfl_xor(s, off, 64);
    if (l == 0) rsP[(size_t)blockIdx.x * 8192 + r0 + rr] = s;
    const float vv[4] = {v.x, v.y, v.z, v.w};
#pragma unroll
    for (int j = 0; j < 4; ++j) {
      const int c = l * 4 + j;
      // element (c, rr) -> row c, phys chunk = (rr>>3) ^ (c>>2 &7), slot rr&7
      const int phys = c * 128 + ((((rr >> 3) ^ (l & 7)) << 4) | ((rr & 7) << 1));
      *(u16*)(Tsm + phys) = f2bf(vv[j]);
    }
  }
  __syncthreads();
#pragma unroll
  for (int it = 0; it < 8; ++it) {
    const int chunk = it * 256 + tid;         // 2048 chunks of 16B
    const int c = chunk >> 3, part = chunk & 7;
    const int pc = part ^ ((c >> 2) & 7);
    const float4 v = *(const float4*)(Tsm + c * 128 + pc * 16);
    *(float4*)((char*)adjT + ((size_t)(c0 + c) * 8192 + r0 + part * 8) * 2) = v;
  }
}

__global__ __launch_bounds__(256) void k_d(const float* __restrict__ rsP,
                                           float* __restrict__ dv) {
  const int i = blockIdx.x * 256 + threadIdx.x;
  float s = 0.f;
#pragma unroll
  for (int cx = 0; cx < 32; ++cx) s += rsP[(size_t)cx * 8192 + i];
  dv[i] = 1.0f / sqrtf(s);
}

__global__ __launch_bounds__(256) void k_prepw(const float* __restrict__ W1,
                                               const float* __restrict__ W2,
                                               u16* __restrict__ W1T,
                                               u16* __restrict__ W2T) {
  const int gid = blockIdx.x * 256 + threadIdx.x;  // < 32768
  { const int n = gid >> 8, c = gid & 255; W1T[gid] = f2bf(W1[c * 128 + n]); }
  if (gid < 8192) { const int n = gid >> 7, c = gid & 127; W2T[gid] = f2bf(W2[c * 64 + n]); }
}

__global__ __launch_bounds__(256) void k_convx(const float4* __restrict__ x,
                                               u16x4* __restrict__ xbf) {
  const int gid = blockIdx.x * 256 + threadIdx.x;  // < 524288
  const float4 v = x[gid];
  u16x4 o; o.x = f2bf(v.x); o.y = f2bf(v.y); o.z = f2bf(v.z); o.w = f2bf(v.w);
  xbf[gid] = o;
}

// ---------------------------------------------------------------------------
// Shared GEMM: C[M=8192, N=BN] = A(bf16, k-contig rows) @ B(bf16, k-contig rows)
// BM=128, BK=64, 4 waves (2x2), 16x16x32 bf16 MFMA, XOR-swizzled LDS staged
// via global_load_lds with pre-swizzled global source (swizzle on both sides).
// EPI=0: f32 split-K partial to Cp[blockIdx.y][m][n].
// EPI=1: final, scale rows by d, write bf16 TRANSPOSED Ut[n][m] (8192-stride).
// ---------------------------------------------------------------------------
template <int BN, int EPI>
__global__ __launch_bounds__(256, 2) void gemm_kern(
    const u16* __restrict__ A, const u16* __restrict__ B,
    const float* __restrict__ dvec, float* __restrict__ Cp, u16* __restrict__ Ut,
    const int lda, const int ldb, const int ksteps) {
  constexpr int NREP = BN / 32;
  __shared__ __align__(16) u16 smem[16384 + 2 * BN * 64];
  const int tid = threadIdx.x, l = tid & 63, w = tid >> 6;
  const int wm = w >> 1, wn = w & 1;
  const int m0 = blockIdx.x * 128;
  const int kbase = blockIdx.y * ksteps * 64;
  const u16* Ag = A + (size_t)m0 * lda + kbase;
  const u16* Bg = B + kbase;
  u16* Asm = smem;            // [2][128*64]
  u16* Bsm = smem + 16384;    // [2][BN*64]

  f32x4v acc[4][NREP];
  const f32x4v zero = {0.f, 0.f, 0.f, 0.f};
#pragma unroll
  for (int mr = 0; mr < 4; ++mr)
#pragma unroll
    for (int nr = 0; nr < NREP; ++nr) acc[mr][nr] = zero;

  auto stageA = [&](int k0, int buf) {
#pragma unroll
    for (int q = 0; q < 4; ++q) {              // 1024 chunks of 16B
      const int c = q * 256 + tid;
      const int row = c >> 3;
      const int kp = (c & 7) ^ (row & 7);      // inverse-swizzled source
      const u16* src = Ag + (size_t)row * lda + k0 + kp * 8;
      u16* dst = Asm + buf * 8192 + (q * 256 + (tid & ~63)) * 8;  // wave-uniform
      GLOAD_LDS16(src, dst);
    }
  };
  auto stageB = [&](int k0, int buf) {
#pragma unroll
    for (int q = 0; q < BN / 32; ++q) {        // BN*8 chunks
      const int c = q * 256 + tid;
      const int row = c >> 3;
      const int kp = (c & 7) ^ (row & 7);
      const u16* src = Bg + (size_t)row * ldb + k0 + kp * 8;
      u16* dst = Bsm + buf * (BN * 64) + (q * 256 + (tid & ~63)) * 8;
      GLOAD_LDS16(src, dst);
    }
  };

  stageA(0, 0);
  stageB(0, 0);

  for (int t = 0; t < ksteps; ++t) {
    const int cur = t & 1;
    __syncthreads();  // drains this wave's loads -> buf[cur] ready for all
    if (t + 1 < ksteps) { stageA((t + 1) * 64, cur ^ 1); stageB((t + 1) * 64, cur ^ 1); }
    const char* Ab = (const char*)(Asm + cur * 8192);
    const char* Bb = (const char*)(Bsm + cur * (BN * 64));
#pragma unroll
    for (int kk = 0; kk < 2; ++kk) {
      short8v a[4], b[NREP];
#pragma unroll
      for (int mr = 0; mr < 4; ++mr) {
        const int row = wm * 64 + mr * 16 + (l & 15);
        const int kb = kk * 64 + ((l >> 4) << 4);
        a[mr] = *(const short8v*)(Ab + row * 128 + (kb ^ ((row & 7) << 4)));
      }
#pragma unroll
      for (int nr = 0; nr < NREP; ++nr) {
        const int row = wn * (BN / 2) + nr * 16 + (l & 15);
        const int kb = kk * 64 + ((l >> 4) << 4);
        b[nr] = *(const short8v*)(Bb + row * 128 + (kb ^ ((row & 7) << 4)));
      }
#pragma unroll
      for (int mr = 0; mr < 4; ++mr)
#pragma unroll
        for (int nr = 0; nr < NREP; ++nr)
          acc[mr][nr] = __builtin_amdgcn_mfma_f32_16x16x32_bf16(a[mr], b[nr],
                                                                acc[mr][nr], 0, 0, 0);
    }
  }

  if (EPI == 0) {
    float* outp = Cp + (size_t)blockIdx.y * ((size_t)8192 * BN);
#pragma unroll
    for (int mr = 0; mr < 4; ++mr)
#pragma unroll
      for (int r = 0; r < 4; ++r) {
        const int m = m0 + wm * 64 + mr * 16 + ((l >> 4) << 2) + r;
#pragma unroll
        for (int nr = 0; nr < NREP; ++nr) {
          const int n = wn * (BN / 2) + nr * 16 + (l & 15);
          outp[(size_t)m * BN + n] = acc[mr][nr][r];
        }
      }
  } else {
    __syncthreads();  // done with stage buffers; reuse as transpose tile
    u16* T = smem;    // [BN][136]
#pragma unroll
    for (int mr = 0; mr < 4; ++mr)
#pragma unroll
      for (int r = 0; r < 4; ++r) {
        const int mloc = wm * 64 + mr * 16 + ((l >> 4) << 2) + r;
        const float dd = dvec[m0 + mloc];
#pragma unroll
        for (int nr = 0; nr < NREP; ++nr) {
          const int n = wn * (BN / 2) + nr * 16 + (l & 15);
          T[n * 136 + mloc] = f2bf(acc[mr][nr][r] * dd);
        }
      }
    __syncthreads();
#pragma unroll
    for (int it = 0; it < BN / 16; ++it) {
      const int chunk = it * 256 + tid;  // BN*16 chunks of 8 elems
      const int n = chunk >> 4, part = chunk & 15;
      const float4 v = *(const float4*)(T + n * 136 + part * 8);
      *(float4*)((char*)Ut + ((size_t)n * 8192 + m0 + part * 8) * 2) = v;
    }
  }
}

// h = relu(d .* (sum_s T1p) + b1) -> bf16 [8192][128]
__global__ __launch_bounds__(256) void k_e1(const float4* __restrict__ P,
                                            const float* __restrict__ dv,
                                            const float* __restrict__ b1,
                                            u16x4* __restrict__ h) {
  const int gid = blockIdx.x * 256 + threadIdx.x;  // < 262144
  const int STR = 262144;
  const float4 s0 = P[gid], s1 = P[gid + STR], s2 = P[gid + 2 * STR], s3 = P[gid + 3 * STR];
  const float dd = dv[gid >> 5];
  const float4 bb = ((const float4*)b1)[gid & 31];
  u16x4 o;
  o.x = f2bf(fmaxf(fmaf(dd, s0.x + s1.x + s2.x + s3.x, bb.x), 0.f));
  o.y = f2bf(fmaxf(fmaf(dd, s0.y + s1.y + s2.y + s3.y, bb.y), 0.f));
  o.z = f2bf(fmaxf(fmaf(dd, s0.z + s1.z + s2.z + s3.z, bb.z), 0.f));
  o.w = f2bf(fmaxf(fmaf(dd, s0.w + s1.w + s2.w + s3.w, bb.w), 0.f));
  h[gid] = o;
}

// out = d .* (sum_s T2p) + b2 -> f32 [8192][64]
__global__ __launch_bounds__(256) void k_e2(const float4* __restrict__ P,
                                            const float* __restrict__ dv,
                                            const float* __restrict__ b2,
                                            float4* __restrict__ out) {
  const int gid = blockIdx.x * 256 + threadIdx.x;  // < 131072
  const int STR = 131072;
  const float4 s0 = P[gid], s1 = P[gid + STR], s2 = P[gid + 2 * STR], s3 = P[gid + 3 * STR];
  const float dd = dv[gid >> 4];
  const float4 bb = ((const float4*)b2)[gid & 15];
  float4 r;
  r.x = fmaf(dd, s0.x + s1.x + s2.x + s3.x, bb.x);
  r.y = fmaf(dd, s0.y + s1.y + s2.y + s3.y, bb.y);
  r.z = fmaf(dd, s0.z + s1.z + s2.z + s3.z, bb.z);
  r.w = fmaf(dd, s0.w + s1.w + s2.w + s3.w, bb.w);
  out[gid] = r;
}

extern "C" void kernel_launch(void* const* d_in, const int* in_sizes, int n_in,
                              void* d_out, int out_size, void* d_ws, size_t ws_size,
                              hipStream_t stream) {
  (void)in_sizes; (void)n_in; (void)out_size; (void)ws_size;
  const float* x   = (const float*)d_in[0];
  const float* adj = (const float*)d_in[1];
  const float* W1  = (const float*)d_in[2];
  const float* b1  = (const float*)d_in[3];
  const float* W2  = (const float*)d_in[4];
  const float* b2  = (const float*)d_in[5];
  float* out = (float*)d_out;
  char* ws = (char*)d_ws;

  // ws layout (bytes), total ~162.1 MB
  u16*   adjT = (u16*)(ws + 0ull);              // 8192*8192 bf16 = 128 MB (adj^T)
  float* T1p  = (float*)(ws + 134217728ull);    // 4*8192*128 f32 = 16 MB
  float* T2p  = (float*)(ws + 151005184ull);    // 4*8192*64  f32 =  8 MB
  u16*   xbf  = (u16*)(ws + 159393792ull);      // 8192*256 bf16  =  4 MB
  u16*   hbf  = (u16*)(ws + 163588096ull);      // 8192*128 bf16  =  2 MB
  u16*   U1T  = (u16*)(ws + 165685248ull);      // 128*8192 bf16  =  2 MB
  u16*   U2T  = (u16*)(ws + 167782400ull);      // 64*8192 bf16   =  1 MB
  u16*   W1T  = (u16*)(ws + 168830976ull);      // 128*256 bf16
  u16*   W2T  = (u16*)(ws + 168896512ull);      // 64*128 bf16
  float* rsP  = (float*)(ws + 168912896ull);    // 32*8192 f32 partial rowsums
  float* dv   = (float*)(ws + 169961472ull);    // 8192 f32

  k_prepw<<<128, 256, 0, stream>>>(W1, W2, W1T, W2T);
  k_convx<<<2048, 256, 0, stream>>>((const float4*)x, (u16x4*)xbf);
  k_adj<<<dim3(32, 128), 256, 0, stream>>>(adj, adjT, rsP);
  k_d<<<32, 256, 0, stream>>>(rsP, dv);
  // U1T[n][j] = d[j] * (x @ W1)[j][n]
  gemm_kern<128, 1><<<dim3(64, 1), 256, 0, stream>>>(xbf, W1T, dv, nullptr, U1T, 256, 256, 4);
  // T1p[s] = partial adjT @ U1T^T
  gemm_kern<128, 0><<<dim3(64, 4), 256, 0, stream>>>(adjT, U1T, nullptr, T1p, nullptr, 8192, 8192, 32);
  k_e1<<<1024, 256, 0, stream>>>((const float4*)T1p, dv, b1, (u16x4*)hbf);
  // U2T[n][j] = d[j] * (h @ W2)[j][n]
  gemm_kern<64, 1><<<dim3(64, 1), 256, 0, stream>>>(hbf, W2T, dv, nullptr, U2T, 128, 128, 2);
  // T2p[s] = partial adjT @ U2T^T
  gemm_kern<64, 0><<<dim3(64, 4), 256, 0, stream>>>(adjT, U2T, nullptr, T2p, nullptr, 8192, 8192, 32);
  k_e2<<<512, 256, 0, stream>>>((const float4*)T2p, dv, b2, (float4*)out);
}

// Round 2
// 182.697 us; speedup vs baseline: 1.0420x; 1.0420x over previous
//
#include <hip/hip_runtime.h>
#include <math.h>

typedef unsigned short u16;
typedef __attribute__((ext_vector_type(8))) short short8v;
typedef __attribute__((ext_vector_type(4))) float f32x4v;
typedef __attribute__((ext_vector_type(4))) unsigned short u16x4;

#define GLOAD_LDS16(src, dst)                                      \
  __builtin_amdgcn_global_load_lds(                                \
      (const __attribute__((address_space(1))) void*)(src),        \
      (__attribute__((address_space(3))) void*)(dst), 16, 0, 0)

__device__ __forceinline__ u16 f2bf(float f) {
  union { float f; unsigned u; } v; v.f = f;
  unsigned r = v.u + 0x7FFFu + ((v.u >> 16) & 1u);  // RNE
  return (u16)(r >> 16);
}

// ---------------------------------------------------------------------------
// K_adj: read adj f32 once; per-block partial row sums (deterministic, 128
// column-slices) and bf16 TRANSPOSED copy adjT[i][j] = adj[j][i] via LDS.
// Tile: 64 rows x 256 cols. grid = (32, 128). Loads hoisted 8-wide for MLP.
// ---------------------------------------------------------------------------
__global__ __launch_bounds__(256) void k_adj(const float* __restrict__ adj,
                                             u16* __restrict__ adjT,
                                             float* __restrict__ rsP) {
  __shared__ __align__(16) char Tsm[32768];  // 256 rows(c) x 128B, chunk-swizzled
  const int tid = threadIdx.x, l = tid & 63, w = tid >> 6;
  const int c0 = blockIdx.x * 256, r0 = blockIdx.y * 64;
  const int g = l >> 4;  // 16-lane group: covers c-subrange [64g, 64g+64)
#pragma unroll
  for (int pp = 0; pp < 2; ++pp) {
    float4 v[8];
#pragma unroll
    for (int q = 0; q < 8; ++q) {
      const int rr = (pp * 8 + q) * 4 + w;
      v[q] = *(const float4*)(adj + (size_t)(r0 + rr) * 8192 + c0 + l * 4);
    }
#pragma unroll
    for (int q = 0; q < 8; ++q) {
      const int rr = (pp * 8 + q) * 4 + w;
      float s = v[q].x + v[q].y + v[q].z + v[q].w;
#pragma unroll
      for (int off = 8; off > 0; off >>= 1) s += __shfl_xor(s, off, 64);
      if ((l & 15) == 0)
        rsP[(size_t)(blockIdx.x * 4 + g) * 8192 + r0 + rr] = s;
      const float vv[4] = {v[q].x, v[q].y, v[q].z, v[q].w};
#pragma unroll
      for (int j = 0; j < 4; ++j) {
        const int c = l * 4 + j;
        // element (c, rr) -> row c, phys chunk = (rr>>3) ^ (c>>2 &7), slot rr&7
        const int phys = c * 128 + ((((rr >> 3) ^ (l & 7)) << 4) | ((rr & 7) << 1));
        *(u16*)(Tsm + phys) = f2bf(vv[j]);
      }
    }
  }
  __syncthreads();
#pragma unroll
  for (int it = 0; it < 8; ++it) {
    const int chunk = it * 256 + tid;         // 2048 chunks of 16B
    const int c = chunk >> 3, part = chunk & 7;
    const int pc = part ^ ((c >> 2) & 7);
    const float4 v = *(const float4*)(Tsm + c * 128 + pc * 16);
    *(float4*)((char*)adjT + ((size_t)(c0 + c) * 8192 + r0 + part * 8) * 2) = v;
  }
}

__global__ __launch_bounds__(256) void k_d(const float* __restrict__ rsP,
                                           float* __restrict__ dv) {
  const int i = blockIdx.x * 256 + threadIdx.x;
  float s = 0.f;
#pragma unroll 8
  for (int cx = 0; cx < 128; ++cx) s += rsP[(size_t)cx * 8192 + i];
  dv[i] = 1.0f / sqrtf(s);
}

// Fused: x f32 -> bf16, W1/W2 -> bf16 transposed
__global__ __launch_bounds__(256) void k_prep(const float4* __restrict__ x,
                                              u16x4* __restrict__ xbf,
                                              const float* __restrict__ W1,
                                              const float* __restrict__ W2,
                                              u16* __restrict__ W1T,
                                              u16* __restrict__ W2T) {
  const int gid = blockIdx.x * 256 + threadIdx.x;  // < 524288
  const float4 v = x[gid];
  u16x4 o; o.x = f2bf(v.x); o.y = f2bf(v.y); o.z = f2bf(v.z); o.w = f2bf(v.w);
  xbf[gid] = o;
  if (gid < 32768) { const int n = gid >> 8, c = gid & 255; W1T[gid] = f2bf(W1[c * 128 + n]); }
  if (gid < 8192)  { const int n = gid >> 7, c = gid & 127; W2T[gid] = f2bf(W2[c * 64 + n]); }
}

// ---------------------------------------------------------------------------
// Shared GEMM: C[M=8192, N=BN] = A(bf16, k-contig rows) @ B(bf16, k-contig rows)
// BM x BK=64 tile, 4 waves (2x2), 16x16x32 bf16 MFMA, XOR-swizzled LDS staged
// via global_load_lds with pre-swizzled global source (swizzle on both sides).
// BM=64 -> 48KB LDS max -> 2+ blocks/CU at grid 512 for latency overlap.
// EPI=0: f32 split-K partial to Cp[blockIdx.y][m][n].
// EPI=1: final, scale rows by d, write bf16 TRANSPOSED Ut[n][m] (8192-stride).
// ---------------------------------------------------------------------------
template <int BM, int BN, int EPI>
__global__ __launch_bounds__(256, 2) void gemm_kern(
    const u16* __restrict__ A, const u16* __restrict__ B,
    const float* __restrict__ dvec, float* __restrict__ Cp, u16* __restrict__ Ut,
    const int lda, const int ldb, const int ksteps) {
  constexpr int MREP = BM / 32;
  constexpr int NREP = BN / 32;
  __shared__ __align__(16) u16 smem[2 * BM * 64 + 2 * BN * 64];
  const int tid = threadIdx.x, l = tid & 63, w = tid >> 6;
  const int wm = w >> 1, wn = w & 1;
  const int m0 = blockIdx.x * BM;
  const int kbase = blockIdx.y * ksteps * 64;
  const u16* Ag = A + (size_t)m0 * lda + kbase;
  const u16* Bg = B + kbase;
  u16* Asm = smem;                 // [2][BM*64]
  u16* Bsm = smem + 2 * BM * 64;   // [2][BN*64]

  f32x4v acc[MREP][NREP];
  const f32x4v zero = {0.f, 0.f, 0.f, 0.f};
#pragma unroll
  for (int mr = 0; mr < MREP; ++mr)
#pragma unroll
    for (int nr = 0; nr < NREP; ++nr) acc[mr][nr] = zero;

  auto stageA = [&](int k0, int buf) {
#pragma unroll
    for (int q = 0; q < BM / 32; ++q) {        // BM*8 chunks of 16B
      const int c = q * 256 + tid;
      const int row = c >> 3;
      const int kp = (c & 7) ^ (row & 7);      // inverse-swizzled source
      const u16* src = Ag + (size_t)row * lda + k0 + kp * 8;
      u16* dst = Asm + buf * (BM * 64) + (q * 256 + (tid & ~63)) * 8;  // wave-uniform
      GLOAD_LDS16(src, dst);
    }
  };
  auto stageB = [&](int k0, int buf) {
#pragma unroll
    for (int q = 0; q < BN / 32; ++q) {        // BN*8 chunks
      const int c = q * 256 + tid;
      const int row = c >> 3;
      const int kp = (c & 7) ^ (row & 7);
      const u16* src = Bg + (size_t)row * ldb + k0 + kp * 8;
      u16* dst = Bsm + buf * (BN * 64) + (q * 256 + (tid & ~63)) * 8;
      GLOAD_LDS16(src, dst);
    }
  };

  stageA(0, 0);
  stageB(0, 0);

  for (int t = 0; t < ksteps; ++t) {
    const int cur = t & 1;
    __syncthreads();  // drains this wave's loads -> buf[cur] ready for all
    if (t + 1 < ksteps) { stageA((t + 1) * 64, cur ^ 1); stageB((t + 1) * 64, cur ^ 1); }
    const char* Ab = (const char*)(Asm + cur * (BM * 64));
    const char* Bb = (const char*)(Bsm + cur * (BN * 64));
#pragma unroll
    for (int kk = 0; kk < 2; ++kk) {
      short8v a[MREP], b[NREP];
#pragma unroll
      for (int mr = 0; mr < MREP; ++mr) {
        const int row = wm * (BM / 2) + mr * 16 + (l & 15);
        const int kb = kk * 64 + ((l >> 4) << 4);
        a[mr] = *(const short8v*)(Ab + row * 128 + (kb ^ ((row & 7) << 4)));
      }
#pragma unroll
      for (int nr = 0; nr < NREP; ++nr) {
        const int row = wn * (BN / 2) + nr * 16 + (l & 15);
        const int kb = kk * 64 + ((l >> 4) << 4);
        b[nr] = *(const short8v*)(Bb + row * 128 + (kb ^ ((row & 7) << 4)));
      }
#pragma unroll
      for (int mr = 0; mr < MREP; ++mr)
#pragma unroll
        for (int nr = 0; nr < NREP; ++nr)
          acc[mr][nr] = __builtin_amdgcn_mfma_f32_16x16x32_bf16(a[mr], b[nr],
                                                                acc[mr][nr], 0, 0, 0);
    }
  }

  if (EPI == 0) {
    float* outp = Cp + (size_t)blockIdx.y * ((size_t)8192 * BN);
#pragma unroll
    for (int mr = 0; mr < MREP; ++mr)
#pragma unroll
      for (int r = 0; r < 4; ++r) {
        const int m = m0 + wm * (BM / 2) + mr * 16 + ((l >> 4) << 2) + r;
#pragma unroll
        for (int nr = 0; nr < NREP; ++nr) {
          const int n = wn * (BN / 2) + nr * 16 + (l & 15);
          outp[(size_t)m * BN + n] = acc[mr][nr][r];
        }
      }
  } else {
    __syncthreads();  // done with stage buffers; reuse as transpose tile
    u16* T = smem;    // [BN][BM+8]
#pragma unroll
    for (int mr = 0; mr < MREP; ++mr)
#pragma unroll
      for (int r = 0; r < 4; ++r) {
        const int mloc = wm * (BM / 2) + mr * 16 + ((l >> 4) << 2) + r;
        const float dd = dvec[m0 + mloc];
#pragma unroll
        for (int nr = 0; nr < NREP; ++nr) {
          const int n = wn * (BN / 2) + nr * 16 + (l & 15);
          T[n * (BM + 8) + mloc] = f2bf(acc[mr][nr][r] * dd);
        }
      }
    __syncthreads();
#pragma unroll
    for (int it = 0; it < (BN * (BM / 8)) / 256; ++it) {
      const int chunk = it * 256 + tid;  // BN*(BM/8) chunks of 8 elems
      const int n = chunk / (BM / 8), part = chunk & (BM / 8 - 1);
      const float4 v = *(const float4*)(T + n * (BM + 8) + part * 8);
      *(float4*)((char*)Ut + ((size_t)n * 8192 + m0 + part * 8) * 2) = v;
    }
  }
}

// h = relu(d .* (sum_s T1p) + b1) -> bf16 [8192][128]
__global__ __launch_bounds__(256) void k_e1(const float4* __restrict__ P,
                                            const float* __restrict__ dv,
                                            const float* __restrict__ b1,
                                            u16x4* __restrict__ h) {
  const int gid = blockIdx.x * 256 + threadIdx.x;  // < 262144
  const int STR = 262144;
  const float4 s0 = P[gid], s1 = P[gid + STR], s2 = P[gid + 2 * STR], s3 = P[gid + 3 * STR];
  const float dd = dv[gid >> 5];
  const float4 bb = ((const float4*)b1)[gid & 31];
  u16x4 o;
  o.x = f2bf(fmaxf(fmaf(dd, s0.x + s1.x + s2.x + s3.x, bb.x), 0.f));
  o.y = f2bf(fmaxf(fmaf(dd, s0.y + s1.y + s2.y + s3.y, bb.y), 0.f));
  o.z = f2bf(fmaxf(fmaf(dd, s0.z + s1.z + s2.z + s3.z, bb.z), 0.f));
  o.w = f2bf(fmaxf(fmaf(dd, s0.w + s1.w + s2.w + s3.w, bb.w), 0.f));
  h[gid] = o;
}

// out = d .* (sum_s T2p) + b2 -> f32 [8192][64]
__global__ __launch_bounds__(256) void k_e2(const float4* __restrict__ P,
                                            const float* __restrict__ dv,
                                            const float* __restrict__ b2,
                                            float4* __restrict__ out) {
  const int gid = blockIdx.x * 256 + threadIdx.x;  // < 131072
  const int STR = 131072;
  const float4 s0 = P[gid], s1 = P[gid + STR], s2 = P[gid + 2 * STR], s3 = P[gid + 3 * STR];
  const float dd = dv[gid >> 4];
  const float4 bb = ((const float4*)b2)[gid & 15];
  float4 r;
  r.x = fmaf(dd, s0.x + s1.x + s2.x + s3.x, bb.x);
  r.y = fmaf(dd, s0.y + s1.y + s2.y + s3.y, bb.y);
  r.z = fmaf(dd, s0.z + s1.z + s2.z + s3.z, bb.z);
  r.w = fmaf(dd, s0.w + s1.w + s2.w + s3.w, bb.w);
  out[gid] = r;
}

extern "C" void kernel_launch(void* const* d_in, const int* in_sizes, int n_in,
                              void* d_out, int out_size, void* d_ws, size_t ws_size,
                              hipStream_t stream) {
  (void)in_sizes; (void)n_in; (void)out_size; (void)ws_size;
  const float* x   = (const float*)d_in[0];
  const float* adj = (const float*)d_in[1];
  const float* W1  = (const float*)d_in[2];
  const float* b1  = (const float*)d_in[3];
  const float* W2  = (const float*)d_in[4];
  const float* b2  = (const float*)d_in[5];
  float* out = (float*)d_out;
  char* ws = (char*)d_ws;

  // ws layout (bytes), total ~169 MB
  u16*   adjT = (u16*)(ws + 0ull);              // 8192*8192 bf16 = 128 MB (adj^T)
  float* T1p  = (float*)(ws + 134217728ull);    // 4*8192*128 f32 = 16 MB
  float* T2p  = (float*)(ws + 151005184ull);    // 4*8192*64  f32 =  8 MB
  u16*   xbf  = (u16*)(ws + 159393792ull);      // 8192*256 bf16  =  4 MB
  u16*   hbf  = (u16*)(ws + 163588096ull);      // 8192*128 bf16  =  2 MB
  u16*   U1T  = (u16*)(ws + 165685248ull);      // 128*8192 bf16  =  2 MB
  u16*   U2T  = (u16*)(ws + 167782400ull);      // 64*8192 bf16   =  1 MB
  u16*   W1T  = (u16*)(ws + 168830976ull);      // 128*256 bf16
  u16*   W2T  = (u16*)(ws + 168896512ull);      // 64*128 bf16
  float* dv   = (float*)(ws + 168912896ull);    // 8192 f32
  // rsP (128*8192 f32 = 4 MB) aliases T1p: dead before T1p is written
  float* rsP  = T1p;

  k_prep<<<2048, 256, 0, stream>>>((const float4*)x, (u16x4*)xbf, W1, W2, W1T, W2T);
  k_adj<<<dim3(32, 128), 256, 0, stream>>>(adj, adjT, rsP);
  k_d<<<32, 256, 0, stream>>>(rsP, dv);
  // U1T[n][j] = d[j] * (x @ W1)[j][n]
  gemm_kern<64, 128, 1><<<dim3(128, 1), 256, 0, stream>>>(xbf, W1T, dv, nullptr, U1T, 256, 256, 4);
  // T1p[s] = partial adjT @ U1T^T
  gemm_kern<64, 128, 0><<<dim3(128, 4), 256, 0, stream>>>(adjT, U1T, nullptr, T1p, nullptr, 8192, 8192, 32);
  k_e1<<<1024, 256, 0, stream>>>((const float4*)T1p, dv, b1, (u16x4*)hbf);
  // U2T[n][j] = d[j] * (h @ W2)[j][n]
  gemm_kern<64, 64, 1><<<dim3(128, 1), 256, 0, stream>>>(hbf, W2T, dv, nullptr, U2T, 128, 128, 2);
  // T2p[s] = partial adjT @ U2T^T
  gemm_kern<64, 64, 0><<<dim3(128, 4), 256, 0, stream>>>(adjT, U2T, nullptr, T2p, nullptr, 8192, 8192, 32);
  k_e2<<<512, 256, 0, stream>>>((const float4*)T2p, dv, b2, (float4*)out);
}

// Round 4
// 180.937 us; speedup vs baseline: 1.0521x; 1.0097x over previous
//
#include <hip/hip_runtime.h>
#include <math.h>

typedef unsigned short u16;
typedef __attribute__((ext_vector_type(8))) short short8v;
typedef __attribute__((ext_vector_type(4))) float f32x4v;
typedef __attribute__((ext_vector_type(4))) unsigned short u16x4;

#define GLOAD_LDS16(src, dst)                                      \
  __builtin_amdgcn_global_load_lds(                                \
      (const __attribute__((address_space(1))) void*)(src),        \
      (__attribute__((address_space(3))) void*)(dst), 16, 0, 0)

__device__ __forceinline__ u16 f2bf(float f) {
  union { float f; unsigned u; } v; v.f = f;
  unsigned r = v.u + 0x7FFFu + ((v.u >> 16) & 1u);  // RNE
  return (u16)(r >> 16);
}

// ---------------------------------------------------------------------------
// K_adj (fused with prep): read adj f32 once; per-block partial row sums
// (128 column-slices) and bf16 TRANSPOSED copy adjT[i][j] = adj[j][i].
// Transpose: 4 named float4 rows per pass -> u16x4 column packs ->
// ds_write_b64 at slot (p*4+w)^(l&15) (bijective; 4 words/bank = wave64
// minimum, conflict-free). ALL indices compile-time; no pointer-swapped
// register arrays (round-3 suspect construct removed).
// Tile: 64 rows x 256 cols. grid = (32, 128).
// ---------------------------------------------------------------------------
__global__ __launch_bounds__(256) void k_adj(const float* __restrict__ adj,
                                             u16* __restrict__ adjT,
                                             float* __restrict__ rsP,
                                             const float4* __restrict__ x,
                                             u16x4* __restrict__ xbf,
                                             const float* __restrict__ W1,
                                             const float* __restrict__ W2,
                                             u16* __restrict__ W1T,
                                             u16* __restrict__ W2T) {
  __shared__ __align__(16) char Tsm[32768];  // 256 c-rows x 16 slots x 8B
  const int tid = threadIdx.x, l = tid & 63, w = tid >> 6;
  const int bx = blockIdx.x, by = blockIdx.y;
  const int c0 = bx * 256, r0 = by * 64;
  const int flat = by * 32 + bx;  // 0..4095

  // ---- fused prep (independent streaming work) ----
  if (tid < 128) {
    const int gid = flat * 128 + tid;  // covers 524288 float4 of x exactly
    const float4 v = x[gid];
    u16x4 o; o.x = f2bf(v.x); o.y = f2bf(v.y); o.z = f2bf(v.z); o.w = f2bf(v.w);
    xbf[gid] = o;
  }
  if (flat < 128) { const int gid = flat * 256 + tid; const int n = gid >> 8, c = gid & 255; W1T[gid] = f2bf(W1[c * 128 + n]); }
  if (flat < 32)  { const int gid = flat * 256 + tid; const int n = gid >> 7, c = gid & 127; W2T[gid] = f2bf(W2[c * 64 + n]); }

  const int g = l >> 4;
  const size_t rowbase = (size_t)(r0 + w * 4) * 8192 + c0 + l * 4;
#pragma unroll
  for (int p = 0; p < 4; ++p) {
    // rows r0 + p*16 + w*4 + {0,1,2,3}, cols c0 + l*4 + {0..3}
    const float4 r0v = *(const float4*)(adj + rowbase + (size_t)(p * 16 + 0) * 8192);
    const float4 r1v = *(const float4*)(adj + rowbase + (size_t)(p * 16 + 1) * 8192);
    const float4 r2v = *(const float4*)(adj + rowbase + (size_t)(p * 16 + 2) * 8192);
    const float4 r3v = *(const float4*)(adj + rowbase + (size_t)(p * 16 + 3) * 8192);
    const int rrb = p * 16 + w * 4;
    // rowsums: width-16 butterfly; slice = bx*4 + g covers cols c0+64g..+63
    {
      float s = r0v.x + r0v.y + r0v.z + r0v.w;
      s += __shfl_xor(s, 8, 64); s += __shfl_xor(s, 4, 64);
      s += __shfl_xor(s, 2, 64); s += __shfl_xor(s, 1, 64);
      if ((l & 15) == 0) rsP[(size_t)(bx * 4 + g) * 8192 + r0 + rrb + 0] = s;
    }
    {
      float s = r1v.x + r1v.y + r1v.z + r1v.w;
      s += __shfl_xor(s, 8, 64); s += __shfl_xor(s, 4, 64);
      s += __shfl_xor(s, 2, 64); s += __shfl_xor(s, 1, 64);
      if ((l & 15) == 0) rsP[(size_t)(bx * 4 + g) * 8192 + r0 + rrb + 1] = s;
    }
    {
      float s = r2v.x + r2v.y + r2v.z + r2v.w;
      s += __shfl_xor(s, 8, 64); s += __shfl_xor(s, 4, 64);
      s += __shfl_xor(s, 2, 64); s += __shfl_xor(s, 1, 64);
      if ((l & 15) == 0) rsP[(size_t)(bx * 4 + g) * 8192 + r0 + rrb + 2] = s;
    }
    {
      float s = r3v.x + r3v.y + r3v.z + r3v.w;
      s += __shfl_xor(s, 8, 64); s += __shfl_xor(s, 4, 64);
      s += __shfl_xor(s, 2, 64); s += __shfl_xor(s, 1, 64);
      if ((l & 15) == 0) rsP[(size_t)(bx * 4 + g) * 8192 + r0 + rrb + 3] = s;
    }
    // column packs: Tsm row c = l*4+j, logical slot q = p*4+w holds rr quad
    // rrb..rrb+3; physical slot = q ^ (l&15)  [mask == (c>>2)&15 since c>>2==l]
    const int slot = (p * 4 + w) ^ (l & 15);
    {
      u16x4 pk; pk.x = f2bf(r0v.x); pk.y = f2bf(r1v.x); pk.z = f2bf(r2v.x); pk.w = f2bf(r3v.x);
      *(u16x4*)(Tsm + (l * 4 + 0) * 128 + slot * 8) = pk;
    }
    {
      u16x4 pk; pk.x = f2bf(r0v.y); pk.y = f2bf(r1v.y); pk.z = f2bf(r2v.y); pk.w = f2bf(r3v.y);
      *(u16x4*)(Tsm + (l * 4 + 1) * 128 + slot * 8) = pk;
    }
    {
      u16x4 pk; pk.x = f2bf(r0v.z); pk.y = f2bf(r1v.z); pk.z = f2bf(r2v.z); pk.w = f2bf(r3v.z);
      *(u16x4*)(Tsm + (l * 4 + 2) * 128 + slot * 8) = pk;
    }
    {
      u16x4 pk; pk.x = f2bf(r0v.w); pk.y = f2bf(r1v.w); pk.z = f2bf(r2v.w); pk.w = f2bf(r3v.w);
      *(u16x4*)(Tsm + (l * 4 + 3) * 128 + slot * 8) = pk;
    }
  }
  __syncthreads();
  // ---- read-out: 2048 chunks of 16B (2x b64 at inverse-swizzled slots) ----
#pragma unroll
  for (int it = 0; it < 8; ++it) {
    const int chunk = it * 256 + tid;
    const int c = chunk >> 3, part = chunk & 7;
    const int m = (c >> 2) & 15;
    const int s0 = (part * 2) ^ m, s1 = (part * 2 + 1) ^ m;
    const float2 lo = *(const float2*)(Tsm + c * 128 + s0 * 8);
    const float2 hi = *(const float2*)(Tsm + c * 128 + s1 * 8);
    float4 o; o.x = lo.x; o.y = lo.y; o.z = hi.x; o.w = hi.y;
    *(float4*)((char*)adjT + ((size_t)(c0 + c) * 8192 + r0 + part * 8) * 2) = o;
  }
}

__global__ __launch_bounds__(256) void k_d(const float* __restrict__ rsP,
                                           float* __restrict__ dv) {
  const int i = blockIdx.x * 256 + threadIdx.x;
  float s = 0.f;
#pragma unroll 8
  for (int cx = 0; cx < 128; ++cx) s += rsP[(size_t)cx * 8192 + i];
  dv[i] = 1.0f / sqrtf(s);
}

// ---------------------------------------------------------------------------
// Shared GEMM (round-2 proven, unchanged): C[M=8192,N=BN] = A @ B, both bf16
// k-contig rows. BM x BK=64 tile, 4 waves (2x2), 16x16x32 bf16 MFMA,
// XOR-swizzled LDS staged via global_load_lds w/ pre-swizzled global source.
// EPI=0: f32 split-K partial to Cp[blockIdx.y][m][n].
// EPI=1: final, scale rows by d, write bf16 TRANSPOSED Ut[n][m] (8192-stride).
// ---------------------------------------------------------------------------
template <int BM, int BN, int EPI>
__global__ __launch_bounds__(256, 2) void gemm_kern(
    const u16* __restrict__ A, const u16* __restrict__ B,
    const float* __restrict__ dvec, float* __restrict__ Cp, u16* __restrict__ Ut,
    const int lda, const int ldb, const int ksteps) {
  constexpr int MREP = BM / 32;
  constexpr int NREP = BN / 32;
  __shared__ __align__(16) u16 smem[2 * BM * 64 + 2 * BN * 64];
  const int tid = threadIdx.x, l = tid & 63, w = tid >> 6;
  const int wm = w >> 1, wn = w & 1;
  const int m0 = blockIdx.x * BM;
  const int kbase = blockIdx.y * ksteps * 64;
  const u16* Ag = A + (size_t)m0 * lda + kbase;
  const u16* Bg = B + kbase;
  u16* Asm = smem;                 // [2][BM*64]
  u16* Bsm = smem + 2 * BM * 64;   // [2][BN*64]

  f32x4v acc[MREP][NREP];
  const f32x4v zero = {0.f, 0.f, 0.f, 0.f};
#pragma unroll
  for (int mr = 0; mr < MREP; ++mr)
#pragma unroll
    for (int nr = 0; nr < NREP; ++nr) acc[mr][nr] = zero;

  auto stageA = [&](int k0, int buf) {
#pragma unroll
    for (int q = 0; q < BM / 32; ++q) {        // BM*8 chunks of 16B
      const int c = q * 256 + tid;
      const int row = c >> 3;
      const int kp = (c & 7) ^ (row & 7);      // inverse-swizzled source
      const u16* src = Ag + (size_t)row * lda + k0 + kp * 8;
      u16* dst = Asm + buf * (BM * 64) + (q * 256 + (tid & ~63)) * 8;  // wave-uniform
      GLOAD_LDS16(src, dst);
    }
  };
  auto stageB = [&](int k0, int buf) {
#pragma unroll
    for (int q = 0; q < BN / 32; ++q) {        // BN*8 chunks
      const int c = q * 256 + tid;
      const int row = c >> 3;
      const int kp = (c & 7) ^ (row & 7);
      const u16* src = Bg + (size_t)row * ldb + k0 + kp * 8;
      u16* dst = Bsm + buf * (BN * 64) + (q * 256 + (tid & ~63)) * 8;
      GLOAD_LDS16(src, dst);
    }
  };

  stageA(0, 0);
  stageB(0, 0);

  for (int t = 0; t < ksteps; ++t) {
    const int cur = t & 1;
    __syncthreads();  // drains this wave's loads -> buf[cur] ready for all
    if (t + 1 < ksteps) { stageA((t + 1) * 64, cur ^ 1); stageB((t + 1) * 64, cur ^ 1); }
    const char* Ab = (const char*)(Asm + cur * (BM * 64));
    const char* Bb = (const char*)(Bsm + cur * (BN * 64));
#pragma unroll
    for (int kk = 0; kk < 2; ++kk) {
      short8v a[MREP], b[NREP];
#pragma unroll
      for (int mr = 0; mr < MREP; ++mr) {
        const int row = wm * (BM / 2) + mr * 16 + (l & 15);
        const int kb = kk * 64 + ((l >> 4) << 4);
        a[mr] = *(const short8v*)(Ab + row * 128 + (kb ^ ((row & 7) << 4)));
      }
#pragma unroll
      for (int nr = 0; nr < NREP; ++nr) {
        const int row = wn * (BN / 2) + nr * 16 + (l & 15);
        const int kb = kk * 64 + ((l >> 4) << 4);
        b[nr] = *(const short8v*)(Bb + row * 128 + (kb ^ ((row & 7) << 4)));
      }
#pragma unroll
      for (int mr = 0; mr < MREP; ++mr)
#pragma unroll
        for (int nr = 0; nr < NREP; ++nr)
          acc[mr][nr] = __builtin_amdgcn_mfma_f32_16x16x32_bf16(a[mr], b[nr],
                                                                acc[mr][nr], 0, 0, 0);
    }
  }

  if (EPI == 0) {
    float* outp = Cp + (size_t)blockIdx.y * ((size_t)8192 * BN);
#pragma unroll
    for (int mr = 0; mr < MREP; ++mr)
#pragma unroll
      for (int r = 0; r < 4; ++r) {
        const int m = m0 + wm * (BM / 2) + mr * 16 + ((l >> 4) << 2) + r;
#pragma unroll
        for (int nr = 0; nr < NREP; ++nr) {
          const int n = wn * (BN / 2) + nr * 16 + (l & 15);
          outp[(size_t)m * BN + n] = acc[mr][nr][r];
        }
      }
  } else {
    __syncthreads();  // done with stage buffers; reuse as transpose tile
    u16* T = smem;    // [BN][BM+8]
#pragma unroll
    for (int mr = 0; mr < MREP; ++mr)
#pragma unroll
      for (int r = 0; r < 4; ++r) {
        const int mloc = wm * (BM / 2) + mr * 16 + ((l >> 4) << 2) + r;
        const float dd = dvec[m0 + mloc];
#pragma unroll
        for (int nr = 0; nr < NREP; ++nr) {
          const int n = wn * (BN / 2) + nr * 16 + (l & 15);
          T[n * (BM + 8) + mloc] = f2bf(acc[mr][nr][r] * dd);
        }
      }
    __syncthreads();
#pragma unroll
    for (int it = 0; it < (BN * (BM / 8)) / 256; ++it) {
      const int chunk = it * 256 + tid;  // BN*(BM/8) chunks of 8 elems
      const int n = chunk / (BM / 8), part = chunk & (BM / 8 - 1);
      const float4 v = *(const float4*)(T + n * (BM + 8) + part * 8);
      *(float4*)((char*)Ut + ((size_t)n * 8192 + m0 + part * 8) * 2) = v;
    }
  }
}

// h = relu(d .* (sum_s T1p) + b1) -> bf16 [8192][128]
__global__ __launch_bounds__(256) void k_e1(const float4* __restrict__ P,
                                            const float* __restrict__ dv,
                                            const float* __restrict__ b1,
                                            u16x4* __restrict__ h) {
  const int gid = blockIdx.x * 256 + threadIdx.x;  // < 262144
  const int STR = 262144;
  const float4 s0 = P[gid], s1 = P[gid + STR], s2 = P[gid + 2 * STR], s3 = P[gid + 3 * STR];
  const float dd = dv[gid >> 5];
  const float4 bb = ((const float4*)b1)[gid & 31];
  u16x4 o;
  o.x = f2bf(fmaxf(fmaf(dd, s0.x + s1.x + s2.x + s3.x, bb.x), 0.f));
  o.y = f2bf(fmaxf(fmaf(dd, s0.y + s1.y + s2.y + s3.y, bb.y), 0.f));
  o.z = f2bf(fmaxf(fmaf(dd, s0.z + s1.z + s2.z + s3.z, bb.z), 0.f));
  o.w = f2bf(fmaxf(fmaf(dd, s0.w + s1.w + s2.w + s3.w, bb.w), 0.f));
  h[gid] = o;
}

// out = d .* (sum_s T2p) + b2 -> f32 [8192][64]
__global__ __launch_bounds__(256) void k_e2(const float4* __restrict__ P,
                                            const float* __restrict__ dv,
                                            const float* __restrict__ b2,
                                            float4* __restrict__ out) {
  const int gid = blockIdx.x * 256 + threadIdx.x;  // < 131072
  const int STR = 131072;
  const float4 s0 = P[gid], s1 = P[gid + STR], s2 = P[gid + 2 * STR], s3 = P[gid + 3 * STR];
  const float dd = dv[gid >> 4];
  const float4 bb = ((const float4*)b2)[gid & 15];
  float4 r;
  r.x = fmaf(dd, s0.x + s1.x + s2.x + s3.x, bb.x);
  r.y = fmaf(dd, s0.y + s1.y + s2.y + s3.y, bb.y);
  r.z = fmaf(dd, s0.z + s1.z + s2.z + s3.z, bb.z);
  r.w = fmaf(dd, s0.w + s1.w + s2.w + s3.w, bb.w);
  out[gid] = r;
}

extern "C" void kernel_launch(void* const* d_in, const int* in_sizes, int n_in,
                              void* d_out, int out_size, void* d_ws, size_t ws_size,
                              hipStream_t stream) {
  (void)in_sizes; (void)n_in; (void)out_size; (void)ws_size;
  const float* x   = (const float*)d_in[0];
  const float* adj = (const float*)d_in[1];
  const float* W1  = (const float*)d_in[2];
  const float* b1  = (const float*)d_in[3];
  const float* W2  = (const float*)d_in[4];
  const float* b2  = (const float*)d_in[5];
  float* out = (float*)d_out;
  char* ws = (char*)d_ws;

  // ws layout (bytes), total ~161 MB
  u16*   adjT = (u16*)(ws + 0ull);              // 8192*8192 bf16 = 128 MB (adj^T)
  float* T1p  = (float*)(ws + 134217728ull);    // 4*8192*128 f32 = 16 MB
  float* T2p  = (float*)(ws + 151005184ull);    // 4*8192*64  f32 =  8 MB
  u16*   xbf  = (u16*)(ws + 159393792ull);      // 8192*256 bf16  =  4 MB
  u16*   hbf  = (u16*)(ws + 163588096ull);      // 8192*128 bf16  =  2 MB
  u16*   U1T  = (u16*)(ws + 165685248ull);      // 128*8192 bf16  =  2 MB
  u16*   U2T  = (u16*)(ws + 167782400ull);      // 64*8192 bf16   =  1 MB
  u16*   W1T  = (u16*)(ws + 168830976ull);      // 128*256 bf16
  u16*   W2T  = (u16*)(ws + 168896512ull);      // 64*128 bf16
  float* dv   = (float*)(ws + 168912896ull);    // 8192 f32
  // rsP (128*8192 f32 = 4 MB) aliases T1p: dead before T1p is written
  float* rsP  = T1p;

  k_adj<<<dim3(32, 128), 256, 0, stream>>>(adj, adjT, rsP,
                                           (const float4*)x, (u16x4*)xbf,
                                           W1, W2, W1T, W2T);
  k_d<<<32, 256, 0, stream>>>(rsP, dv);
  // U1T[n][j] = d[j] * (x @ W1)[j][n]
  gemm_kern<64, 128, 1><<<dim3(128, 1), 256, 0, stream>>>(
      xbf, W1T, dv, nullptr, U1T, 256, 256, 4);
  // T1p[s] = partial adjT @ U1T^T
  gemm_kern<64, 128, 0><<<dim3(128, 4), 256, 0, stream>>>(
      adjT, U1T, nullptr, T1p, nullptr, 8192, 8192, 32);
  k_e1<<<1024, 256, 0, stream>>>((const float4*)T1p, dv, b1, (u16x4*)hbf);
  // U2T[n][j] = d[j] * (h @ W2)[j][n]
  gemm_kern<64, 64, 1><<<dim3(128, 1), 256, 0, stream>>>(
      hbf, W2T, dv, nullptr, U2T, 128, 128, 2);
  // T2p[s] = partial adjT @ U2T^T
  gemm_kern<64, 64, 0><<<dim3(128, 4), 256, 0, stream>>>(
      adjT, U2T, nullptr, T2p, nullptr, 8192, 8192, 32);
  k_e2<<<512, 256, 0, stream>>>((const float4*)T2p, dv, b2, (float4*)out);
}

// Round 5
// 171.599 us; speedup vs baseline: 1.1094x; 1.0544x over previous
//
#include <hip/hip_runtime.h>
#include <math.h>

typedef unsigned short u16;
typedef __attribute__((ext_vector_type(8))) short short8v;
typedef __attribute__((ext_vector_type(4))) float f32x4v;
typedef __attribute__((ext_vector_type(4))) unsigned short u16x4;

#define GLOAD_LDS16(src, dst)                                      \
  __builtin_amdgcn_global_load_lds(                                \
      (const __attribute__((address_space(1))) void*)(src),        \
      (__attribute__((address_space(3))) void*)(dst), 16, 0, 0)

__device__ __forceinline__ u16 f2bf(float f) {
  union { float f; unsigned u; } v; v.f = f;
  unsigned r = v.u + 0x7FFFu + ((v.u >> 16) & 1u);  // RNE
  return (u16)(r >> 16);
}

// ---------------------------------------------------------------------------
// K_adj (round-4 proven, unchanged): read adj f32 once; partial row sums
// (128 column-slices) + bf16 TRANSPOSED copy via conflict-free b64 XOR-slot
// LDS transpose. Fused x->bf16 and W1/W2->bf16-transposed prep.
// ---------------------------------------------------------------------------
__global__ __launch_bounds__(256) void k_adj(const float* __restrict__ adj,
                                             u16* __restrict__ adjT,
                                             float* __restrict__ rsP,
                                             const float4* __restrict__ x,
                                             u16x4* __restrict__ xbf,
                                             const float* __restrict__ W1,
                                             const float* __restrict__ W2,
                                             u16* __restrict__ W1T,
                                             u16* __restrict__ W2T) {
  __shared__ __align__(16) char Tsm[32768];  // 256 c-rows x 16 slots x 8B
  const int tid = threadIdx.x, l = tid & 63, w = tid >> 6;
  const int bx = blockIdx.x, by = blockIdx.y;
  const int c0 = bx * 256, r0 = by * 64;
  const int flat = by * 32 + bx;  // 0..4095

  if (tid < 128) {
    const int gid = flat * 128 + tid;  // covers 524288 float4 of x exactly
    const float4 v = x[gid];
    u16x4 o; o.x = f2bf(v.x); o.y = f2bf(v.y); o.z = f2bf(v.z); o.w = f2bf(v.w);
    xbf[gid] = o;
  }
  if (flat < 128) { const int gid = flat * 256 + tid; const int n = gid >> 8, c = gid & 255; W1T[gid] = f2bf(W1[c * 128 + n]); }
  if (flat < 32)  { const int gid = flat * 256 + tid; const int n = gid >> 7, c = gid & 127; W2T[gid] = f2bf(W2[c * 64 + n]); }

  const int g = l >> 4;
  const size_t rowbase = (size_t)(r0 + w * 4) * 8192 + c0 + l * 4;
#pragma unroll
  for (int p = 0; p < 4; ++p) {
    const float4 r0v = *(const float4*)(adj + rowbase + (size_t)(p * 16 + 0) * 8192);
    const float4 r1v = *(const float4*)(adj + rowbase + (size_t)(p * 16 + 1) * 8192);
    const float4 r2v = *(const float4*)(adj + rowbase + (size_t)(p * 16 + 2) * 8192);
    const float4 r3v = *(const float4*)(adj + rowbase + (size_t)(p * 16 + 3) * 8192);
    const int rrb = p * 16 + w * 4;
    {
      float s = r0v.x + r0v.y + r0v.z + r0v.w;
      s += __shfl_xor(s, 8, 64); s += __shfl_xor(s, 4, 64);
      s += __shfl_xor(s, 2, 64); s += __shfl_xor(s, 1, 64);
      if ((l & 15) == 0) rsP[(size_t)(bx * 4 + g) * 8192 + r0 + rrb + 0] = s;
    }
    {
      float s = r1v.x + r1v.y + r1v.z + r1v.w;
      s += __shfl_xor(s, 8, 64); s += __shfl_xor(s, 4, 64);
      s += __shfl_xor(s, 2, 64); s += __shfl_xor(s, 1, 64);
      if ((l & 15) == 0) rsP[(size_t)(bx * 4 + g) * 8192 + r0 + rrb + 1] = s;
    }
    {
      float s = r2v.x + r2v.y + r2v.z + r2v.w;
      s += __shfl_xor(s, 8, 64); s += __shfl_xor(s, 4, 64);
      s += __shfl_xor(s, 2, 64); s += __shfl_xor(s, 1, 64);
      if ((l & 15) == 0) rsP[(size_t)(bx * 4 + g) * 8192 + r0 + rrb + 2] = s;
    }
    {
      float s = r3v.x + r3v.y + r3v.z + r3v.w;
      s += __shfl_xor(s, 8, 64); s += __shfl_xor(s, 4, 64);
      s += __shfl_xor(s, 2, 64); s += __shfl_xor(s, 1, 64);
      if ((l & 15) == 0) rsP[(size_t)(bx * 4 + g) * 8192 + r0 + rrb + 3] = s;
    }
    const int slot = (p * 4 + w) ^ (l & 15);
    {
      u16x4 pk; pk.x = f2bf(r0v.x); pk.y = f2bf(r1v.x); pk.z = f2bf(r2v.x); pk.w = f2bf(r3v.x);
      *(u16x4*)(Tsm + (l * 4 + 0) * 128 + slot * 8) = pk;
    }
    {
      u16x4 pk; pk.x = f2bf(r0v.y); pk.y = f2bf(r1v.y); pk.z = f2bf(r2v.y); pk.w = f2bf(r3v.y);
      *(u16x4*)(Tsm + (l * 4 + 1) * 128 + slot * 8) = pk;
    }
    {
      u16x4 pk; pk.x = f2bf(r0v.z); pk.y = f2bf(r1v.z); pk.z = f2bf(r2v.z); pk.w = f2bf(r3v.z);
      *(u16x4*)(Tsm + (l * 4 + 2) * 128 + slot * 8) = pk;
    }
    {
      u16x4 pk; pk.x = f2bf(r0v.w); pk.y = f2bf(r1v.w); pk.z = f2bf(r2v.w); pk.w = f2bf(r3v.w);
      *(u16x4*)(Tsm + (l * 4 + 3) * 128 + slot * 8) = pk;
    }
  }
  __syncthreads();
#pragma unroll
  for (int it = 0; it < 8; ++it) {
    const int chunk = it * 256 + tid;
    const int c = chunk >> 3, part = chunk & 7;
    const int m = (c >> 2) & 15;
    const int s0 = (part * 2) ^ m, s1 = (part * 2 + 1) ^ m;
    const float2 lo = *(const float2*)(Tsm + c * 128 + s0 * 8);
    const float2 hi = *(const float2*)(Tsm + c * 128 + s1 * 8);
    float4 o; o.x = lo.x; o.y = lo.y; o.z = hi.x; o.w = hi.y;
    *(float4*)((char*)adjT + ((size_t)(c0 + c) * 8192 + r0 + part * 8) * 2) = o;
  }
}

// ---------------------------------------------------------------------------
// Shared GEMM (round-2/4 proven body). DSRC: 0 = no d; 1 = read dvec;
// 2 = compute d from rsP BEFORE staging (own barrier pair), publish dvout.
// EPI=0: f32 split-K partial. EPI=1: d-scale rows, bf16 transposed Ut.
// ---------------------------------------------------------------------------
template <int BM, int BN, int EPI, int DSRC>
__global__ __launch_bounds__(256, 2) void gemm_kern(
    const u16* __restrict__ A, const u16* __restrict__ B,
    const float* __restrict__ dvec, const float* __restrict__ rsP,
    float* __restrict__ dvout, float* __restrict__ Cp, u16* __restrict__ Ut,
    const int lda, const int ldb, const int ksteps) {
  constexpr int MREP = BM / 32;
  constexpr int NREP = BN / 32;
  __shared__ __align__(16) u16 smem[2 * BM * 64 + 2 * BN * 64];
  __shared__ float psum[(DSRC == 2) ? 4 : 1][64];
  __shared__ float dv_sm[(DSRC == 2) ? 64 : 1];
  const int tid = threadIdx.x, l = tid & 63, w = tid >> 6;
  const int wm = w >> 1, wn = w & 1;
  const int m0 = blockIdx.x * BM;
  const int kbase = blockIdx.y * ksteps * 64;
  const u16* Ag = A + (size_t)m0 * lda + kbase;
  const u16* Bg = B + kbase;
  u16* Asm = smem;                 // [2][BM*64]
  u16* Bsm = smem + 2 * BM * 64;   // [2][BN*64]

  if (DSRC == 2) {
    // dv[m0+i] = rsqrt(sum over 128 rsP slices); runs before any staging
    float s = 0.f;
    const float* rp = rsP + (size_t)(w * 32) * 8192 + m0 + l;
#pragma unroll 8
    for (int q = 0; q < 32; ++q) s += rp[(size_t)q * 8192];
    psum[w][l] = s;
    __syncthreads();
    if (tid < 64) {
      const float dd = 1.0f / sqrtf(psum[0][tid] + psum[1][tid] + psum[2][tid] + psum[3][tid]);
      dv_sm[tid] = dd;
      dvout[m0 + tid] = dd;
    }
    __syncthreads();
  }

  f32x4v acc[MREP][NREP];
  const f32x4v zero = {0.f, 0.f, 0.f, 0.f};
#pragma unroll
  for (int mr = 0; mr < MREP; ++mr)
#pragma unroll
    for (int nr = 0; nr < NREP; ++nr) acc[mr][nr] = zero;

  auto stageA = [&](int k0, int buf) {
#pragma unroll
    for (int q = 0; q < BM / 32; ++q) {        // BM*8 chunks of 16B
      const int c = q * 256 + tid;
      const int row = c >> 3;
      const int kp = (c & 7) ^ (row & 7);      // inverse-swizzled source
      const u16* src = Ag + (size_t)row * lda + k0 + kp * 8;
      u16* dst = Asm + buf * (BM * 64) + (q * 256 + (tid & ~63)) * 8;  // wave-uniform
      GLOAD_LDS16(src, dst);
    }
  };
  auto stageB = [&](int k0, int buf) {
#pragma unroll
    for (int q = 0; q < BN / 32; ++q) {        // BN*8 chunks
      const int c = q * 256 + tid;
      const int row = c >> 3;
      const int kp = (c & 7) ^ (row & 7);
      const u16* src = Bg + (size_t)row * ldb + k0 + kp * 8;
      u16* dst = Bsm + buf * (BN * 64) + (q * 256 + (tid & ~63)) * 8;
      GLOAD_LDS16(src, dst);
    }
  };

  stageA(0, 0);
  stageB(0, 0);

  for (int t = 0; t < ksteps; ++t) {
    const int cur = t & 1;
    __syncthreads();  // drains this wave's loads -> buf[cur] ready for all
    if (t + 1 < ksteps) { stageA((t + 1) * 64, cur ^ 1); stageB((t + 1) * 64, cur ^ 1); }
    const char* Ab = (const char*)(Asm + cur * (BM * 64));
    const char* Bb = (const char*)(Bsm + cur * (BN * 64));
#pragma unroll
    for (int kk = 0; kk < 2; ++kk) {
      short8v a[MREP], b[NREP];
#pragma unroll
      for (int mr = 0; mr < MREP; ++mr) {
        const int row = wm * (BM / 2) + mr * 16 + (l & 15);
        const int kb = kk * 64 + ((l >> 4) << 4);
        a[mr] = *(const short8v*)(Ab + row * 128 + (kb ^ ((row & 7) << 4)));
      }
#pragma unroll
      for (int nr = 0; nr < NREP; ++nr) {
        const int row = wn * (BN / 2) + nr * 16 + (l & 15);
        const int kb = kk * 64 + ((l >> 4) << 4);
        b[nr] = *(const short8v*)(Bb + row * 128 + (kb ^ ((row & 7) << 4)));
      }
#pragma unroll
      for (int mr = 0; mr < MREP; ++mr)
#pragma unroll
        for (int nr = 0; nr < NREP; ++nr)
          acc[mr][nr] = __builtin_amdgcn_mfma_f32_16x16x32_bf16(a[mr], b[nr],
                                                                acc[mr][nr], 0, 0, 0);
    }
  }

  if (EPI == 0) {
    float* outp = Cp + (size_t)blockIdx.y * ((size_t)8192 * BN);
#pragma unroll
    for (int mr = 0; mr < MREP; ++mr)
#pragma unroll
      for (int r = 0; r < 4; ++r) {
        const int m = m0 + wm * (BM / 2) + mr * 16 + ((l >> 4) << 2) + r;
#pragma unroll
        for (int nr = 0; nr < NREP; ++nr) {
          const int n = wn * (BN / 2) + nr * 16 + (l & 15);
          outp[(size_t)m * BN + n] = acc[mr][nr][r];
        }
      }
  } else {
    __syncthreads();  // done with stage buffers; reuse as transpose tile
    u16* T = smem;    // [BN][BM+8]
#pragma unroll
    for (int mr = 0; mr < MREP; ++mr)
#pragma unroll
      for (int r = 0; r < 4; ++r) {
        const int mloc = wm * (BM / 2) + mr * 16 + ((l >> 4) << 2) + r;
        const float dd = (DSRC == 2) ? dv_sm[mloc] : dvec[m0 + mloc];
#pragma unroll
        for (int nr = 0; nr < NREP; ++nr) {
          const int n = wn * (BN / 2) + nr * 16 + (l & 15);
          T[n * (BM + 8) + mloc] = f2bf(acc[mr][nr][r] * dd);
        }
      }
    __syncthreads();
#pragma unroll
    for (int it = 0; it < (BN * (BM / 8)) / 256; ++it) {
      const int chunk = it * 256 + tid;  // BN*(BM/8) chunks of 8 elems
      const int n = chunk / (BM / 8), part = chunk & (BM / 8 - 1);
      const float4 v = *(const float4*)(T + n * (BM + 8) + part * 8);
      *(float4*)((char*)Ut + ((size_t)n * 8192 + m0 + part * 8) * 2) = v;
    }
  }
}

// ---------------------------------------------------------------------------
// k_g3: fused e1 + gemm3. Per block (64 output rows): build A-tile
// h[m][k] = relu(dv[m]*sum_s T1p[s][m][k] + b1[k]) directly into swizzled
// LDS (bank-balanced ds_write_b64), stage B=W2T via global_load_lds,
// 2 K-steps of MFMA, EPI=1-style epilogue -> U2T (bf16 transposed, d-scaled).
// Kills the hbf global round-trip and the k_e1 launch.
// ---------------------------------------------------------------------------
__global__ __launch_bounds__(256, 2) void k_g3(const float* __restrict__ T1p,
                                               const u16* __restrict__ W2T,
                                               const float* __restrict__ dv,
                                               const float* __restrict__ b1,
                                               u16* __restrict__ U2T) {
  __shared__ __align__(16) u16 smem[2 * 4096 + 2 * 4096];  // A | B, 32 KB
  const int tid = threadIdx.x, l = tid & 63, w = tid >> 6;
  const int wm = w >> 1, wn = w & 1;
  const int m0 = blockIdx.x * 64;
  u16* Asm = smem;
  u16* Bsm = smem + 8192;

  // stage B: W2T [64 n][128 k] -> 2 k-buffers, proven swizzled layout
#pragma unroll
  for (int buf = 0; buf < 2; ++buf)
#pragma unroll
    for (int q = 0; q < 2; ++q) {
      const int c = q * 256 + tid;         // 512 chunks of 16B per buffer
      const int row = c >> 3;
      const int kp = (c & 7) ^ (row & 7);
      const u16* src = W2T + row * 128 + buf * 64 + kp * 8;
      u16* dst = Bsm + buf * 4096 + (q * 256 + (tid & ~63)) * 8;
      GLOAD_LDS16(src, dst);
    }

  // build A: 2048 float4 positions (row 0..63, n4 0..31)
  const float* P0 = T1p + (size_t)m0 * 128;
#pragma unroll
  for (int it = 0; it < 8; ++it) {
    const int f = it * 256 + tid;
    const int row = f >> 5, n4 = f & 31;
    const float* p = P0 + (size_t)row * 128 + n4 * 4;
    const float4 s0 = *(const float4*)(p);
    const float4 s1 = *(const float4*)(p + (size_t)1048576);   // 8192*128
    const float4 s2 = *(const float4*)(p + (size_t)2097152);
    const float4 s3 = *(const float4*)(p + (size_t)3145728);
    const float dd = dv[m0 + row];
    const float4 bb = ((const float4*)b1)[n4];
    u16x4 pk;
    pk.x = f2bf(fmaxf(fmaf(dd, s0.x + s1.x + s2.x + s3.x, bb.x), 0.f));
    pk.y = f2bf(fmaxf(fmaf(dd, s0.y + s1.y + s2.y + s3.y, bb.y), 0.f));
    pk.z = f2bf(fmaxf(fmaf(dd, s0.z + s1.z + s2.z + s3.z, bb.z), 0.f));
    pk.w = f2bf(fmaxf(fmaf(dd, s0.w + s1.w + s2.w + s3.w, bb.w), 0.f));
    const int kc_g = n4 >> 1;              // global 8-elem k-chunk 0..15
    const int buf = kc_g >> 3, kc = kc_g & 7;
    const int slot = kc ^ (row & 7);
    *(u16x4*)((char*)Asm + buf * 8192 + row * 128 + slot * 16 + (n4 & 1) * 8) = pk;
  }
  __syncthreads();  // drains global_load_lds (B) and ds_writes (A)

  f32x4v acc[2][2];
  const f32x4v zero = {0.f, 0.f, 0.f, 0.f};
#pragma unroll
  for (int mr = 0; mr < 2; ++mr)
#pragma unroll
    for (int nr = 0; nr < 2; ++nr) acc[mr][nr] = zero;

#pragma unroll
  for (int t = 0; t < 2; ++t) {
    const char* Ab = (const char*)(Asm + t * 4096);
    const char* Bb = (const char*)(Bsm + t * 4096);
#pragma unroll
    for (int kk = 0; kk < 2; ++kk) {
      short8v a[2], b[2];
#pragma unroll
      for (int mr = 0; mr < 2; ++mr) {
        const int row = wm * 32 + mr * 16 + (l & 15);
        const int kb = kk * 64 + ((l >> 4) << 4);
        a[mr] = *(const short8v*)(Ab + row * 128 + (kb ^ ((row & 7) << 4)));
      }
#pragma unroll
      for (int nr = 0; nr < 2; ++nr) {
        const int row = wn * 32 + nr * 16 + (l & 15);
        const int kb = kk * 64 + ((l >> 4) << 4);
        b[nr] = *(const short8v*)(Bb + row * 128 + (kb ^ ((row & 7) << 4)));
      }
#pragma unroll
      for (int mr = 0; mr < 2; ++mr)
#pragma unroll
        for (int nr = 0; nr < 2; ++nr)
          acc[mr][nr] = __builtin_amdgcn_mfma_f32_16x16x32_bf16(a[mr], b[nr],
                                                                acc[mr][nr], 0, 0, 0);
    }
  }

  __syncthreads();  // reuse smem as transpose tile
  u16* T = smem;    // [64][72]
#pragma unroll
  for (int mr = 0; mr < 2; ++mr)
#pragma unroll
    for (int r = 0; r < 4; ++r) {
      const int mloc = wm * 32 + mr * 16 + ((l >> 4) << 2) + r;
      const float dd = dv[m0 + mloc];
#pragma unroll
      for (int nr = 0; nr < 2; ++nr) {
        const int n = wn * 32 + nr * 16 + (l & 15);
        T[n * 72 + mloc] = f2bf(acc[mr][nr][r] * dd);
      }
    }
  __syncthreads();
#pragma unroll
  for (int it = 0; it < 2; ++it) {
    const int chunk = it * 256 + tid;  // 512 chunks of 8 elems
    const int n = chunk >> 3, part = chunk & 7;
    const float4 v = *(const float4*)(T + n * 72 + part * 8);
    *(float4*)((char*)U2T + ((size_t)n * 8192 + m0 + part * 8) * 2) = v;
  }
}

// out = d .* (sum_s T2p) + b2 -> f32 [8192][64]
__global__ __launch_bounds__(256) void k_e2(const float4* __restrict__ P,
                                            const float* __restrict__ dv,
                                            const float* __restrict__ b2,
                                            float4* __restrict__ out) {
  const int gid = blockIdx.x * 256 + threadIdx.x;  // < 131072
  const int STR = 131072;
  const float4 s0 = P[gid], s1 = P[gid + STR], s2 = P[gid + 2 * STR], s3 = P[gid + 3 * STR];
  const float dd = dv[gid >> 4];
  const float4 bb = ((const float4*)b2)[gid & 15];
  float4 r;
  r.x = fmaf(dd, s0.x + s1.x + s2.x + s3.x, bb.x);
  r.y = fmaf(dd, s0.y + s1.y + s2.y + s3.y, bb.y);
  r.z = fmaf(dd, s0.z + s1.z + s2.z + s3.z, bb.z);
  r.w = fmaf(dd, s0.w + s1.w + s2.w + s3.w, bb.w);
  out[gid] = r;
}

extern "C" void kernel_launch(void* const* d_in, const int* in_sizes, int n_in,
                              void* d_out, int out_size, void* d_ws, size_t ws_size,
                              hipStream_t stream) {
  (void)in_sizes; (void)n_in; (void)out_size; (void)ws_size;
  const float* x   = (const float*)d_in[0];
  const float* adj = (const float*)d_in[1];
  const float* W1  = (const float*)d_in[2];
  const float* b1  = (const float*)d_in[3];
  const float* W2  = (const float*)d_in[4];
  const float* b2  = (const float*)d_in[5];
  float* out = (float*)d_out;
  char* ws = (char*)d_ws;

  // ws layout (bytes), total ~161 MB
  u16*   adjT = (u16*)(ws + 0ull);              // 8192*8192 bf16 = 128 MB (adj^T)
  float* T1p  = (float*)(ws + 134217728ull);    // 4*8192*128 f32 = 16 MB
  float* T2p  = (float*)(ws + 151005184ull);    // 4*8192*64  f32 =  8 MB
  u16*   xbf  = (u16*)(ws + 159393792ull);      // 8192*256 bf16  =  4 MB
  u16*   U1T  = (u16*)(ws + 165685248ull);      // 128*8192 bf16  =  2 MB
  u16*   U2T  = (u16*)(ws + 167782400ull);      // 64*8192 bf16   =  1 MB
  u16*   W1T  = (u16*)(ws + 168830976ull);      // 128*256 bf16
  u16*   W2T  = (u16*)(ws + 168896512ull);      // 64*128 bf16
  float* dv   = (float*)(ws + 168912896ull);    // 8192 f32
  // rsP (128*8192 f32 = 4 MB) aliases T1p: dead before T1p is written
  float* rsP  = T1p;

  k_adj<<<dim3(32, 128), 256, 0, stream>>>(adj, adjT, rsP,
                                           (const float4*)x, (u16x4*)xbf,
                                           W1, W2, W1T, W2T);
  // U1T[n][j] = d[j] * (x @ W1)[j][n]; computes dv from rsP (fused k_d)
  gemm_kern<64, 128, 1, 2><<<dim3(128, 1), 256, 0, stream>>>(
      xbf, W1T, nullptr, rsP, dv, nullptr, U1T, 256, 256, 4);
  // T1p[s] = partial adjT @ U1T^T
  gemm_kern<64, 128, 0, 0><<<dim3(128, 4), 256, 0, stream>>>(
      adjT, U1T, nullptr, nullptr, nullptr, T1p, nullptr, 8192, 8192, 32);
  // fused e1 + gemm3: U2T[n][j] = d[j] * (relu(d.*sum(T1p)+b1) @ W2)[j][n]
  k_g3<<<128, 256, 0, stream>>>(T1p, W2T, dv, b1, U2T);
  // T2p[s] = partial adjT @ U2T^T
  gemm_kern<64, 64, 0, 0><<<dim3(128, 4), 256, 0, stream>>>(
      adjT, U2T, nullptr, nullptr, nullptr, T2p, nullptr, 8192, 8192, 32);
  k_e2<<<512, 256, 0, stream>>>((const float4*)T2p, dv, b2, (float4*)out);
}

// Round 8
// 154.679 us; speedup vs baseline: 1.2307x; 1.1094x over previous
//
#include <hip/hip_runtime.h>
#include <math.h>

typedef unsigned short u16;
typedef __attribute__((ext_vector_type(8))) short short8v;
typedef __attribute__((ext_vector_type(4))) float f32x4v;
typedef __attribute__((ext_vector_type(4))) unsigned short u16x4;

#define GLOAD_LDS16(src, dst)                                      \
  __builtin_amdgcn_global_load_lds(                                \
      (const __attribute__((address_space(1))) void*)(src),        \
      (__attribute__((address_space(3))) void*)(dst), 16, 0, 0)

__device__ __forceinline__ u16 f2bf(float f) {
  union { float f; unsigned u; } v; v.f = f;
  unsigned r = v.u + 0x7FFFu + ((v.u >> 16) & 1u);  // RNE
  return (u16)(r >> 16);
}

// non-temporal float4 load: stream past L3 so adjT stays resident.
// builtin requires a clang ext_vector pointer, not HIP_vector_type.
__device__ __forceinline__ float4 ntld(const float4* p) {
  const f32x4v v = __builtin_nontemporal_load((const f32x4v*)p);
  float4 r; r.x = v.x; r.y = v.y; r.z = v.z; r.w = v.w;
  return r;
}

// ---------------------------------------------------------------------------
// K_adj: read adj f32 once (NON-TEMPORAL: don't evict adjT from L3);
// partial row sums (128 column-slices) + bf16 TRANSPOSED copy via
// conflict-free b64 XOR-slot LDS transpose. Fused x->bf16 (nt read) and
// W1/W2->bf16-transposed prep.
// ---------------------------------------------------------------------------
__global__ __launch_bounds__(256) void k_adj(const float* __restrict__ adj,
                                             u16* __restrict__ adjT,
                                             float* __restrict__ rsP,
                                             const float4* __restrict__ x,
                                             u16x4* __restrict__ xbf,
                                             const float* __restrict__ W1,
                                             const float* __restrict__ W2,
                                             u16* __restrict__ W1T,
                                             u16* __restrict__ W2T) {
  __shared__ __align__(16) char Tsm[32768];  // 256 c-rows x 16 slots x 8B
  const int tid = threadIdx.x, l = tid & 63, w = tid >> 6;
  const int bx = blockIdx.x, by = blockIdx.y;
  const int c0 = bx * 256, r0 = by * 64;
  const int flat = by * 32 + bx;  // 0..4095

  if (tid < 128) {
    const int gid = flat * 128 + tid;  // covers 524288 float4 of x exactly
    const float4 v = ntld(x + gid);
    u16x4 o; o.x = f2bf(v.x); o.y = f2bf(v.y); o.z = f2bf(v.z); o.w = f2bf(v.w);
    xbf[gid] = o;
  }
  if (flat < 128) { const int gid = flat * 256 + tid; const int n = gid >> 8, c = gid & 255; W1T[gid] = f2bf(W1[c * 128 + n]); }
  if (flat < 32)  { const int gid = flat * 256 + tid; const int n = gid >> 7, c = gid & 127; W2T[gid] = f2bf(W2[c * 64 + n]); }

  const int g = l >> 4;
  const size_t rowbase = (size_t)(r0 + w * 4) * 8192 + c0 + l * 4;
#pragma unroll
  for (int p = 0; p < 4; ++p) {
    const float4 r0v = ntld((const float4*)(adj + rowbase + (size_t)(p * 16 + 0) * 8192));
    const float4 r1v = ntld((const float4*)(adj + rowbase + (size_t)(p * 16 + 1) * 8192));
    const float4 r2v = ntld((const float4*)(adj + rowbase + (size_t)(p * 16 + 2) * 8192));
    const float4 r3v = ntld((const float4*)(adj + rowbase + (size_t)(p * 16 + 3) * 8192));
    const int rrb = p * 16 + w * 4;
    {
      float s = r0v.x + r0v.y + r0v.z + r0v.w;
      s += __shfl_xor(s, 8, 64); s += __shfl_xor(s, 4, 64);
      s += __shfl_xor(s, 2, 64); s += __shfl_xor(s, 1, 64);
      if ((l & 15) == 0) rsP[(size_t)(bx * 4 + g) * 8192 + r0 + rrb + 0] = s;
    }
    {
      float s = r1v.x + r1v.y + r1v.z + r1v.w;
      s += __shfl_xor(s, 8, 64); s += __shfl_xor(s, 4, 64);
      s += __shfl_xor(s, 2, 64); s += __shfl_xor(s, 1, 64);
      if ((l & 15) == 0) rsP[(size_t)(bx * 4 + g) * 8192 + r0 + rrb + 1] = s;
    }
    {
      float s = r2v.x + r2v.y + r2v.z + r2v.w;
      s += __shfl_xor(s, 8, 64); s += __shfl_xor(s, 4, 64);
      s += __shfl_xor(s, 2, 64); s += __shfl_xor(s, 1, 64);
      if ((l & 15) == 0) rsP[(size_t)(bx * 4 + g) * 8192 + r0 + rrb + 2] = s;
    }
    {
      float s = r3v.x + r3v.y + r3v.z + r3v.w;
      s += __shfl_xor(s, 8, 64); s += __shfl_xor(s, 4, 64);
      s += __shfl_xor(s, 2, 64); s += __shfl_xor(s, 1, 64);
      if ((l & 15) == 0) rsP[(size_t)(bx * 4 + g) * 8192 + r0 + rrb + 3] = s;
    }
    const int slot = (p * 4 + w) ^ (l & 15);
    {
      u16x4 pk; pk.x = f2bf(r0v.x); pk.y = f2bf(r1v.x); pk.z = f2bf(r2v.x); pk.w = f2bf(r3v.x);
      *(u16x4*)(Tsm + (l * 4 + 0) * 128 + slot * 8) = pk;
    }
    {
      u16x4 pk; pk.x = f2bf(r0v.y); pk.y = f2bf(r1v.y); pk.z = f2bf(r2v.y); pk.w = f2bf(r3v.y);
      *(u16x4*)(Tsm + (l * 4 + 1) * 128 + slot * 8) = pk;
    }
    {
      u16x4 pk; pk.x = f2bf(r0v.z); pk.y = f2bf(r1v.z); pk.z = f2bf(r2v.z); pk.w = f2bf(r3v.z);
      *(u16x4*)(Tsm + (l * 4 + 2) * 128 + slot * 8) = pk;
    }
    {
      u16x4 pk; pk.x = f2bf(r0v.w); pk.y = f2bf(r1v.w); pk.z = f2bf(r2v.w); pk.w = f2bf(r3v.w);
      *(u16x4*)(Tsm + (l * 4 + 3) * 128 + slot * 8) = pk;
    }
  }
  __syncthreads();
#pragma unroll
  for (int it = 0; it < 8; ++it) {
    const int chunk = it * 256 + tid;
    const int c = chunk >> 3, part = chunk & 7;
    const int m = (c >> 2) & 15;
    const int s0 = (part * 2) ^ m, s1 = (part * 2 + 1) ^ m;
    const float2 lo = *(const float2*)(Tsm + c * 128 + s0 * 8);
    const float2 hi = *(const float2*)(Tsm + c * 128 + s1 * 8);
    float4 o; o.x = lo.x; o.y = lo.y; o.z = hi.x; o.w = hi.y;
    *(float4*)((char*)adjT + ((size_t)(c0 + c) * 8192 + r0 + part * 8) * 2) = o;
  }
}

// ---------------------------------------------------------------------------
// Shared GEMM (proven body). DSRC: 0 = no d; 2 = compute d from rsP BEFORE
// staging (if constexpr so dead code vanishes in DSRC=0 instantiations;
// OOB-guarded so BM=32 overlapping reductions are benign duplicates).
// EPI=0: f32 split-K partial. EPI=1: d-scale rows, bf16 transposed Ut.
// ---------------------------------------------------------------------------
template <int BM, int BN, int EPI, int DSRC>
__global__ __launch_bounds__(256, 2) void gemm_kern(
    const u16* __restrict__ A, const u16* __restrict__ B,
    const float* __restrict__ dvec, const float* __restrict__ rsP,
    float* __restrict__ dvout, float* __restrict__ Cp, u16* __restrict__ Ut,
    const int lda, const int ldb, const int ksteps) {
  constexpr int MREP = BM / 32;
  constexpr int NREP = BN / 32;
  __shared__ __align__(16) u16 smem[2 * BM * 64 + 2 * BN * 64];
  __shared__ float psum[(DSRC == 2) ? 4 : 1][64];
  __shared__ float dv_sm[(DSRC == 2) ? 64 : 1];
  const int tid = threadIdx.x, l = tid & 63, w = tid >> 6;
  const int wm = w >> 1, wn = w & 1;
  const int m0 = blockIdx.x * BM;
  const int kbase = blockIdx.y * ksteps * 64;
  const u16* Ag = A + (size_t)m0 * lda + kbase;
  const u16* Bg = B + kbase;
  u16* Asm = smem;                 // [2][BM*64]
  u16* Bsm = smem + 2 * BM * 64;   // [2][BN*64]

  if constexpr (DSRC == 2) {
    // dv[m0+i] = rsqrt(sum over 128 rsP slices); runs before any staging
    float s = 0.f;
    if (m0 + l < 8192) {
      const float* rp = rsP + (size_t)(w * 32) * 8192 + m0 + l;
#pragma unroll 8
      for (int q = 0; q < 32; ++q) s += rp[(size_t)q * 8192];
    }
    psum[w][l] = s;
    __syncthreads();
    if (tid < 64 && m0 + tid < 8192) {
      const float dd = 1.0f / sqrtf(psum[0][tid] + psum[1][tid] + psum[2][tid] + psum[3][tid]);
      dv_sm[tid] = dd;
      dvout[m0 + tid] = dd;
    }
    __syncthreads();
  }

  f32x4v acc[MREP][NREP];
  const f32x4v zero = {0.f, 0.f, 0.f, 0.f};
#pragma unroll
  for (int mr = 0; mr < MREP; ++mr)
#pragma unroll
    for (int nr = 0; nr < NREP; ++nr) acc[mr][nr] = zero;

  auto stageA = [&](int k0, int buf) {
#pragma unroll
    for (int q = 0; q < BM / 32; ++q) {        // BM*8 chunks of 16B
      const int c = q * 256 + tid;
      const int row = c >> 3;
      const int kp = (c & 7) ^ (row & 7);      // inverse-swizzled source
      const u16* src = Ag + (size_t)row * lda + k0 + kp * 8;
      u16* dst = Asm + buf * (BM * 64) + (q * 256 + (tid & ~63)) * 8;  // wave-uniform
      GLOAD_LDS16(src, dst);
    }
  };
  auto stageB = [&](int k0, int buf) {
#pragma unroll
    for (int q = 0; q < BN / 32; ++q) {        // BN*8 chunks
      const int c = q * 256 + tid;
      const int row = c >> 3;
      const int kp = (c & 7) ^ (row & 7);
      const u16* src = Bg + (size_t)row * ldb + k0 + kp * 8;
      u16* dst = Bsm + buf * (BN * 64) + (q * 256 + (tid & ~63)) * 8;
      GLOAD_LDS16(src, dst);
    }
  };

  stageA(0, 0);
  stageB(0, 0);

  for (int t = 0; t < ksteps; ++t) {
    const int cur = t & 1;
    __syncthreads();  // drains this wave's loads -> buf[cur] ready for all
    if (t + 1 < ksteps) { stageA((t + 1) * 64, cur ^ 1); stageB((t + 1) * 64, cur ^ 1); }
    const char* Ab = (const char*)(Asm + cur * (BM * 64));
    const char* Bb = (const char*)(Bsm + cur * (BN * 64));
#pragma unroll
    for (int kk = 0; kk < 2; ++kk) {
      short8v a[MREP], b[NREP];
#pragma unroll
      for (int mr = 0; mr < MREP; ++mr) {
        const int row = wm * (BM / 2) + mr * 16 + (l & 15);
        const int kb = kk * 64 + ((l >> 4) << 4);
        a[mr] = *(const short8v*)(Ab + row * 128 + (kb ^ ((row & 7) << 4)));
      }
#pragma unroll
      for (int nr = 0; nr < NREP; ++nr) {
        const int row = wn * (BN / 2) + nr * 16 + (l & 15);
        const int kb = kk * 64 + ((l >> 4) << 4);
        b[nr] = *(const short8v*)(Bb + row * 128 + (kb ^ ((row & 7) << 4)));
      }
#pragma unroll
      for (int mr = 0; mr < MREP; ++mr)
#pragma unroll
        for (int nr = 0; nr < NREP; ++nr)
          acc[mr][nr] = __builtin_amdgcn_mfma_f32_16x16x32_bf16(a[mr], b[nr],
                                                                acc[mr][nr], 0, 0, 0);
    }
  }

  if constexpr (EPI == 0) {
    float* outp = Cp + (size_t)blockIdx.y * ((size_t)8192 * BN);
#pragma unroll
    for (int mr = 0; mr < MREP; ++mr)
#pragma unroll
      for (int r = 0; r < 4; ++r) {
        const int m = m0 + wm * (BM / 2) + mr * 16 + ((l >> 4) << 2) + r;
#pragma unroll
        for (int nr = 0; nr < NREP; ++nr) {
          const int n = wn * (BN / 2) + nr * 16 + (l & 15);
          outp[(size_t)m * BN + n] = acc[mr][nr][r];
        }
      }
  } else {
    __syncthreads();  // done with stage buffers; reuse as transpose tile
    u16* T = smem;    // [BN][BM+8]
#pragma unroll
    for (int mr = 0; mr < MREP; ++mr)
#pragma unroll
      for (int r = 0; r < 4; ++r) {
        const int mloc = wm * (BM / 2) + mr * 16 + ((l >> 4) << 2) + r;
        float dd;
        if constexpr (DSRC == 2) dd = dv_sm[mloc];
        else dd = dvec[m0 + mloc];
#pragma unroll
        for (int nr = 0; nr < NREP; ++nr) {
          const int n = wn * (BN / 2) + nr * 16 + (l & 15);
          T[n * (BM + 8) + mloc] = f2bf(acc[mr][nr][r] * dd);
        }
      }
    __syncthreads();
#pragma unroll
    for (int it = 0; it < (BN * (BM / 8)) / 256; ++it) {
      const int chunk = it * 256 + tid;  // BN*(BM/8) chunks of 8 elems
      const int n = chunk / (BM / 8), part = chunk & (BM / 8 - 1);
      const float4 v = *(const float4*)(T + n * (BM + 8) + part * 8);
      *(float4*)((char*)Ut + ((size_t)n * 8192 + m0 + part * 8) * 2) = v;
    }
  }
}

// ---------------------------------------------------------------------------
// k_g3: fused e1 + gemm3, 32-row blocks (grid 256 = 1 block/CU).
// h[m][k] = relu(dv[m]*sum_s T1p[s][m][k] + b1[k]) built straight into
// swizzled LDS; B=W2T via global_load_lds; MFMA; EPI=1-style -> U2T.
// ---------------------------------------------------------------------------
__global__ __launch_bounds__(256, 2) void k_g3(const float* __restrict__ T1p,
                                               const u16* __restrict__ W2T,
                                               const float* __restrict__ dv,
                                               const float* __restrict__ b1,
                                               u16* __restrict__ U2T) {
  __shared__ __align__(16) u16 smem[2 * 2048 + 2 * 4096];  // A(8KB) | B(16KB)
  const int tid = threadIdx.x, l = tid & 63, w = tid >> 6;
  const int wm = w >> 1, wn = w & 1;
  const int m0 = blockIdx.x * 32;
  u16* Asm = smem;
  u16* Bsm = smem + 4096;

  // stage B: W2T [64 n][128 k] -> 2 k-buffers, proven swizzled layout
#pragma unroll
  for (int buf = 0; buf < 2; ++buf)
#pragma unroll
    for (int q = 0; q < 2; ++q) {
      const int c = q * 256 + tid;         // 512 chunks of 16B per buffer
      const int row = c >> 3;
      const int kp = (c & 7) ^ (row & 7);
      const u16* src = W2T + row * 128 + buf * 64 + kp * 8;
      u16* dst = Bsm + buf * 4096 + (q * 256 + (tid & ~63)) * 8;
      GLOAD_LDS16(src, dst);
    }

  // build A: 1024 float4 positions (row 0..31, n4 0..31)
  const float* P0 = T1p + (size_t)m0 * 128;
#pragma unroll
  for (int it = 0; it < 4; ++it) {
    const int f = it * 256 + tid;
    const int row = f >> 5, n4 = f & 31;
    const float* p = P0 + (size_t)row * 128 + n4 * 4;
    const float4 s0 = *(const float4*)(p);
    const float4 s1 = *(const float4*)(p + (size_t)1048576);   // 8192*128
    const float4 s2 = *(const float4*)(p + (size_t)2097152);
    const float4 s3 = *(const float4*)(p + (size_t)3145728);
    const float dd = dv[m0 + row];
    const float4 bb = ((const float4*)b1)[n4];
    u16x4 pk;
    pk.x = f2bf(fmaxf(fmaf(dd, s0.x + s1.x + s2.x + s3.x, bb.x), 0.f));
    pk.y = f2bf(fmaxf(fmaf(dd, s0.y + s1.y + s2.y + s3.y, bb.y), 0.f));
    pk.z = f2bf(fmaxf(fmaf(dd, s0.z + s1.z + s2.z + s3.z, bb.z), 0.f));
    pk.w = f2bf(fmaxf(fmaf(dd, s0.w + s1.w + s2.w + s3.w, bb.w), 0.f));
    const int kc_g = n4 >> 1;              // global 8-elem k-chunk 0..15
    const int buf = kc_g >> 3, kc = kc_g & 7;
    const int slot = kc ^ (row & 7);
    *(u16x4*)((char*)Asm + buf * 4096 + row * 128 + slot * 16 + (n4 & 1) * 8) = pk;
  }
  __syncthreads();  // drains global_load_lds (B) and ds_writes (A)

  f32x4v acc[2];
  const f32x4v zero = {0.f, 0.f, 0.f, 0.f};
  acc[0] = zero; acc[1] = zero;

#pragma unroll
  for (int t = 0; t < 2; ++t) {
    const char* Ab = (const char*)(Asm + t * 2048);
    const char* Bb = (const char*)(Bsm + t * 4096);
#pragma unroll
    for (int kk = 0; kk < 2; ++kk) {
      short8v a0, b[2];
      {
        const int row = wm * 16 + (l & 15);
        const int kb = kk * 64 + ((l >> 4) << 4);
        a0 = *(const short8v*)(Ab + row * 128 + (kb ^ ((row & 7) << 4)));
      }
#pragma unroll
      for (int nr = 0; nr < 2; ++nr) {
        const int row = wn * 32 + nr * 16 + (l & 15);
        const int kb = kk * 64 + ((l >> 4) << 4);
        b[nr] = *(const short8v*)(Bb + row * 128 + (kb ^ ((row & 7) << 4)));
      }
#pragma unroll
      for (int nr = 0; nr < 2; ++nr)
        acc[nr] = __builtin_amdgcn_mfma_f32_16x16x32_bf16(a0, b[nr],
                                                          acc[nr], 0, 0, 0);
    }
  }

  __syncthreads();  // reuse smem as transpose tile
  u16* T = smem;    // [64][40]
#pragma unroll
  for (int r = 0; r < 4; ++r) {
    const int mloc = wm * 16 + ((l >> 4) << 2) + r;
    const float dd = dv[m0 + mloc];
#pragma unroll
    for (int nr = 0; nr < 2; ++nr) {
      const int n = wn * 32 + nr * 16 + (l & 15);
      T[n * 40 + mloc] = f2bf(acc[nr][r] * dd);
    }
  }
  __syncthreads();
  {
    const int chunk = tid;             // 256 chunks of 8 elems
    const int n = chunk >> 2, part = chunk & 3;
    const float4 v = *(const float4*)(T + n * 40 + part * 8);
    *(float4*)((char*)U2T + ((size_t)n * 8192 + m0 + part * 8) * 2) = v;
  }
}

// out = d .* (sum_s T2p) + b2 -> f32 [8192][64]
__global__ __launch_bounds__(256) void k_e2(const float4* __restrict__ P,
                                            const float* __restrict__ dv,
                                            const float* __restrict__ b2,
                                            float4* __restrict__ out) {
  const int gid = blockIdx.x * 256 + threadIdx.x;  // < 131072
  const int STR = 131072;
  const float4 s0 = P[gid], s1 = P[gid + STR], s2 = P[gid + 2 * STR], s3 = P[gid + 3 * STR];
  const float dd = dv[gid >> 4];
  const float4 bb = ((const float4*)b2)[gid & 15];
  float4 r;
  r.x = fmaf(dd, s0.x + s1.x + s2.x + s3.x, bb.x);
  r.y = fmaf(dd, s0.y + s1.y + s2.y + s3.y, bb.y);
  r.z = fmaf(dd, s0.z + s1.z + s2.z + s3.z, bb.z);
  r.w = fmaf(dd, s0.w + s1.w + s2.w + s3.w, bb.w);
  out[gid] = r;
}

extern "C" void kernel_launch(void* const* d_in, const int* in_sizes, int n_in,
                              void* d_out, int out_size, void* d_ws, size_t ws_size,
                              hipStream_t stream) {
  (void)in_sizes; (void)n_in; (void)out_size; (void)ws_size;
  const float* x   = (const float*)d_in[0];
  const float* adj = (const float*)d_in[1];
  const float* W1  = (const float*)d_in[2];
  const float* b1  = (const float*)d_in[3];
  const float* W2  = (const float*)d_in[4];
  const float* b2  = (const float*)d_in[5];
  float* out = (float*)d_out;
  char* ws = (char*)d_ws;

  // ws layout (bytes), total ~161 MB
  u16*   adjT = (u16*)(ws + 0ull);              // 8192*8192 bf16 = 128 MB (adj^T)
  float* T1p  = (float*)(ws + 134217728ull);    // 4*8192*128 f32 = 16 MB
  float* T2p  = (float*)(ws + 151005184ull);    // 4*8192*64  f32 =  8 MB
  u16*   xbf  = (u16*)(ws + 159393792ull);      // 8192*256 bf16  =  4 MB
  u16*   U1T  = (u16*)(ws + 165685248ull);      // 128*8192 bf16  =  2 MB
  u16*   U2T  = (u16*)(ws + 167782400ull);      // 64*8192 bf16   =  1 MB
  u16*   W1T  = (u16*)(ws + 168830976ull);      // 128*256 bf16
  u16*   W2T  = (u16*)(ws + 168896512ull);      // 64*128 bf16
  float* dv   = (float*)(ws + 168912896ull);    // 8192 f32
  // rsP (128*8192 f32 = 4 MB) aliases T1p: dead before T1p is written
  float* rsP  = T1p;

  k_adj<<<dim3(32, 128), 256, 0, stream>>>(adj, adjT, rsP,
                                           (const float4*)x, (u16x4*)xbf,
                                           W1, W2, W1T, W2T);
  // U1T[n][j] = d[j] * (x @ W1)[j][n]; computes dv from rsP (fused k_d)
  gemm_kern<32, 128, 1, 2><<<dim3(256, 1), 256, 0, stream>>>(
      xbf, W1T, nullptr, rsP, dv, nullptr, U1T, 256, 256, 4);
  // T1p[s] = partial adjT @ U1T^T
  gemm_kern<64, 128, 0, 0><<<dim3(128, 4), 256, 0, stream>>>(
      adjT, U1T, nullptr, nullptr, nullptr, T1p, nullptr, 8192, 8192, 32);
  // fused e1 + gemm3: U2T[n][j] = d[j] * (relu(d.*sum(T1p)+b1) @ W2)[j][n]
  k_g3<<<256, 256, 0, stream>>>(T1p, W2T, dv, b1, U2T);
  // T2p[s] = partial adjT @ U2T^T
  gemm_kern<64, 64, 0, 0><<<dim3(128, 4), 256, 0, stream>>>(
      adjT, U2T, nullptr, nullptr, nullptr, T2p, nullptr, 8192, 8192, 32);
  k_e2<<<512, 256, 0, stream>>>((const float4*)T2p, dv, b2, (float4*)out);
}